// Round 1
// baseline (81.335 us; speedup 1.0000x reference)
//
#include <hip/hip_runtime.h>
#include <math.h>

#define NEGV (-10000000000.0f)

constexpr int B  = 16;
constexpr int QL = 32;
constexpr int TN = 10;
constexpr int AL = 10;
constexpr int E  = 300;
constexpr int H  = 256;
constexpr int M  = TN * AL;     // 100
constexpr int NQ = B * QL;      // 512 q slots
constexpr int NA = B * M;       // 1600 alia slots

// workspace layout (in floats)
constexpr size_t OFF_QEMB = 0;                               // NQ*E
constexpr size_t OFF_AEMB = OFF_QEMB + (size_t)NQ * E;       // NA*E
constexpr size_t OFF_QW2  = OFF_AEMB + (size_t)NA * E;       // NQ
constexpr size_t OFF_AW1  = OFF_QW2 + NQ;                    // NA
constexpr size_t OFF_ATT  = OFF_AW1 + NA;                    // NA*QL
constexpr size_t OFF_ALIG = OFF_ATT + (size_t)NA * QL;       // NA*E
constexpr size_t OFF_HALF = OFF_ALIG + (size_t)NA * E;       // 320*H
constexpr size_t WS_FLOATS = OFF_HALF + (size_t)(B * TN * 2) * H;

// ---------------------------------------------------------------------------
// K1: gather + L2-normalize the needed embedding rows; fuse dot with W1/W2.
// grid = NQ + NA blocks, 256 threads. slot < NQ -> q row, else alia row.
// ---------------------------------------------------------------------------
__global__ __launch_bounds__(256) void k1_normalize(
    const int* __restrict__ q, const int* __restrict__ alia,
    const float* __restrict__ emb, const float* __restrict__ sim_w,
    float* __restrict__ ws) {
  int slot = blockIdx.x;
  int tid = threadIdx.x;
  bool is_q = slot < NQ;
  int idx = is_q ? q[slot] : alia[slot - NQ];
  const float* src = emb + (size_t)idx * E;
  const float* W = is_q ? (sim_w + E) : sim_w;   // W2 for q rows, W1 for a rows
  float* dst = ws + (is_q ? (OFF_QEMB + (size_t)slot * E)
                          : (OFF_AEMB + (size_t)(slot - NQ) * E));
  float* dotOut = ws + (is_q ? (OFF_QW2 + slot) : (OFF_AW1 + (slot - NQ)));

  // each thread covers e = tid and e = tid + 256
  float v0 = src[tid];
  float w0 = W[tid];
  float v1 = 0.f, w1 = 0.f;
  int e1 = tid + 256;
  if (e1 < E) { v1 = src[e1]; w1 = W[e1]; }

  float ss = v0 * v0 + v1 * v1;
  float dw = v0 * w0 + v1 * w1;
  #pragma unroll
  for (int off = 32; off > 0; off >>= 1) {
    ss += __shfl_down(ss, off);
    dw += __shfl_down(dw, off);
  }
  __shared__ float r_ss[4], r_dw[4];
  __shared__ float s_scale;
  int wid = tid >> 6, lane = tid & 63;
  if (lane == 0) { r_ss[wid] = ss; r_dw[wid] = dw; }
  __syncthreads();
  if (tid == 0) {
    float tss = r_ss[0] + r_ss[1] + r_ss[2] + r_ss[3];
    float tdw = r_dw[0] + r_dw[1] + r_dw[2] + r_dw[3];
    float nrm = sqrtf(tss);
    float scale = (idx == 0) ? 0.f : (1.f / fmaxf(nrm, 1e-12f));
    s_scale = scale;
    *dotOut = tdw * scale;
  }
  __syncthreads();
  float sc = s_scale;
  dst[tid] = v0 * sc;
  if (e1 < E) dst[e1] = v1 * sc;
}

// ---------------------------------------------------------------------------
// K2a: per (b,m): atten row (32 masked dots), softmax over ql, alig row.
// grid = NA blocks, 256 threads.
// ---------------------------------------------------------------------------
__global__ __launch_bounds__(256) void k2a_atten(
    const int* __restrict__ q, const int* __restrict__ alia,
    const float* __restrict__ sim_w, const float* __restrict__ sim_b,
    float* __restrict__ ws) {
  int bm = blockIdx.x;            // 0..1599
  int b = bm / M;
  int tid = threadIdx.x;

  __shared__ float s_a3[E];       // a_emb row * W3
  __shared__ float s_att[QL], s_p[QL];

  const float* arow = ws + OFF_AEMB + (size_t)bm * E;
  const float* W3 = sim_w + 2 * E;
  for (int e = tid; e < E; e += 256) s_a3[e] = arow[e] * W3[e];
  __syncthreads();

  // 32 q-dots: group g = tid/8 handles q index g with 8 lanes
  int g = tid >> 3, l = tid & 7;
  const float* qrow = ws + OFF_QEMB + (size_t)(b * QL + g) * E;
  float part = 0.f;
  for (int e = l; e < E; e += 8) part += s_a3[e] * qrow[e];
  part += __shfl_xor(part, 4, 8);
  part += __shfl_xor(part, 2, 8);
  part += __shfl_xor(part, 1, 8);
  if (l == 0) {
    float att = ws[OFF_AW1 + bm] + ws[OFF_QW2 + b * QL + g] + part + sim_b[0];
    bool anz = (alia[bm] != 0);
    bool qnz = (q[b * QL + g] != 0);
    if (!(anz && qnz)) att = NEGV;
    s_att[g] = att;
    ws[OFF_ATT + (size_t)bm * QL + g] = att;   // for max_atten later
  }
  __syncthreads();

  // softmax over 32 (redundant mx/sum on all threads via LDS broadcast)
  float mx = -INFINITY;
  #pragma unroll
  for (int j = 0; j < QL; j++) mx = fmaxf(mx, s_att[j]);
  float sum = 0.f;
  #pragma unroll
  for (int j = 0; j < QL; j++) sum += expf(s_att[j] - mx);
  if (tid < QL) s_p[tid] = expf(s_att[tid] - mx) / sum;
  __syncthreads();

  // alig[e] = sum_q p[q] * q_emb[b,q,e]
  float* alig = ws + OFF_ALIG + (size_t)bm * E;
  const float* qbase = ws + OFF_QEMB + (size_t)b * QL * E;
  for (int e = tid; e < E; e += 256) {
    float acc = 0.f;
    #pragma unroll
    for (int j = 0; j < QL; j++) acc += s_p[j] * qbase[(size_t)j * E + e];
    alig[e] = acc;
  }
}

// ---------------------------------------------------------------------------
// K2b: enc GEMM + relu + partial sum over al.
// grid = B*TN*2 = 320 blocks, 256 threads (h = tid). Each block: 5 rows.
// out: ws[OFF_HALF + grp*H + h] = sum_{j in half} relu(enc_in[j] . enc_w[:,h] + b[h])
// ---------------------------------------------------------------------------
__global__ __launch_bounds__(256) void k2b_enc(
    const float* __restrict__ enc_w, const float* __restrict__ enc_b,
    float* __restrict__ ws) {
  int grp = blockIdx.x;           // 0..319 = b*20 + tn*2 + half
  int h = threadIdx.x;
  int b = grp / 20;
  int r = grp % 20;
  int tn = r >> 1, half = r & 1;
  int bm0 = b * M + tn * AL + half * 5;

  const float* __restrict__ alig = ws + OFF_ALIG + (size_t)bm0 * E;
  const float* __restrict__ aemb = ws + OFF_AEMB + (size_t)bm0 * E;

  float acc[5] = {0.f, 0.f, 0.f, 0.f, 0.f};
  #pragma unroll 4
  for (int e = 0; e < E; e++) {
    float w1 = enc_w[e * H + h];
    float w2 = enc_w[(E + e) * H + h];
    #pragma unroll
    for (int j = 0; j < 5; j++) {
      acc[j] += alig[(size_t)j * E + e] * w1;
      acc[j] += aemb[(size_t)j * E + e] * w2;
    }
  }
  float bias = enc_b[h];
  float s = 0.f;
  #pragma unroll
  for (int j = 0; j < 5; j++) s += fmaxf(acc[j] + bias, 0.f);
  ws[OFF_HALF + (size_t)grp * H + h] = s;
}

// ---------------------------------------------------------------------------
// K3: per-b epilogue. grid = B blocks, 256 threads.
// ---------------------------------------------------------------------------
__global__ __launch_bounds__(256) void k3_final(
    const float* __restrict__ els, const float* __restrict__ elo,
    const float* __restrict__ cate,
    const float* __restrict__ qlin_w, const float* __restrict__ qlin_b,
    const float* __restrict__ cls_w, const float* __restrict__ cls_b,
    const float* __restrict__ ws, float* __restrict__ out) {
  int b = blockIdx.x;
  int tid = threadIdx.x;
  __shared__ float s_logit[TN], s_p[TN];
  __shared__ float s_red[4];
  int wid = tid >> 6, lane = tid & 63;

  for (int tn = 0; tn < TN; tn++) {
    int grp0 = b * 20 + tn * 2;
    float v = (ws[OFF_HALF + (size_t)grp0 * H + tid] +
               ws[OFF_HALF + (size_t)(grp0 + 1) * H + tid]) * qlin_w[tid];
    #pragma unroll
    for (int off = 32; off > 0; off >>= 1) v += __shfl_down(v, off);
    if (lane == 0) s_red[wid] = v;
    __syncthreads();
    if (tid == 0) {
      float score = s_red[0] + s_red[1] + s_red[2] + s_red[3] + qlin_b[0];
      float lo = elo[b * TN + tn], ls = els[b * TN + tn];
      float c0 = cate[(b * TN + tn) * 2 + 0];
      float c1 = cate[(b * TN + tn) * 2 + 1];
      float logit = lo * cls_w[0] + ls * cls_w[1] + c0 * cls_w[2] +
                    c1 * cls_w[3] + score * cls_w[4] + cls_b[0];
      bool tm = (ls + lo) != 0.0f;
      s_logit[tn] = tm ? logit : NEGV;
    }
    __syncthreads();   // protects s_red reuse + publishes s_logit[tn]
  }

  if (tid == 0) {
    float mx = -INFINITY;
    for (int t = 0; t < TN; t++) mx = fmaxf(mx, s_logit[t]);
    float sm = 0.f;
    for (int t = 0; t < TN; t++) sm += expf(s_logit[t] - mx);
    for (int t = 0; t < TN; t++) s_p[t] = expf(s_logit[t] - mx) / sm;
  }
  if (tid < TN) out[b * TN + tid] = s_logit[tid];
  __syncthreads();

  if (tid < QL) {
    float sacc = 0.f;
    for (int tn = 0; tn < TN; tn++) {
      float mxa = -INFINITY;
      #pragma unroll
      for (int al = 0; al < AL; al++) {
        mxa = fmaxf(mxa, ws[OFF_ATT + (size_t)(b * M + tn * AL + al) * QL + tid]);
      }
      sacc += s_p[tn] * mxa;
    }
    // softmax over the 32 lanes (all within wave 0)
    float mx = sacc;
    #pragma unroll
    for (int off = 16; off > 0; off >>= 1) mx = fmaxf(mx, __shfl_xor(mx, off, 32));
    float ex = expf(sacc - mx);
    float sm = ex;
    #pragma unroll
    for (int off = 16; off > 0; off >>= 1) sm += __shfl_xor(sm, off, 32);
    out[B * TN + b * QL + tid] = ex / sm;
  }
}

// ---------------------------------------------------------------------------
extern "C" void kernel_launch(void* const* d_in, const int* in_sizes, int n_in,
                              void* d_out, int out_size, void* d_ws, size_t ws_size,
                              hipStream_t stream) {
  const int*   q      = (const int*)  d_in[0];
  const int*   alia   = (const int*)  d_in[1];
  const float* els    = (const float*)d_in[2];
  const float* elo    = (const float*)d_in[3];
  const float* cate   = (const float*)d_in[4];
  const float* emb    = (const float*)d_in[5];
  const float* sim_w  = (const float*)d_in[6];
  const float* sim_b  = (const float*)d_in[7];
  const float* enc_w  = (const float*)d_in[8];
  const float* enc_b  = (const float*)d_in[9];
  const float* qlin_w = (const float*)d_in[10];
  const float* qlin_b = (const float*)d_in[11];
  const float* cls_w  = (const float*)d_in[12];
  const float* cls_b  = (const float*)d_in[13];
  float* out = (float*)d_out;
  float* ws  = (float*)d_ws;

  k1_normalize<<<NQ + NA, 256, 0, stream>>>(q, alia, emb, sim_w, ws);
  k2a_atten<<<NA, 256, 0, stream>>>(q, alia, sim_w, sim_b, ws);
  k2b_enc<<<B * TN * 2, 256, 0, stream>>>(enc_w, enc_b, ws);
  k3_final<<<B, 256, 0, stream>>>(els, elo, cate, qlin_w, qlin_b, cls_w, cls_b,
                                  ws, out);
}

// Round 2
// 72.162 us; speedup vs baseline: 1.1271x; 1.1271x over previous
//
#include <hip/hip_runtime.h>
#include <math.h>

#define NEGV (-10000000000.0f)

constexpr int B  = 16;
constexpr int QL = 32;
constexpr int TN = 10;
constexpr int AL = 10;
constexpr int E  = 300;
constexpr int H  = 256;
constexpr int M  = TN * AL;     // 100
constexpr int NQ = B * QL;      // 512 q slots
constexpr int NA = B * M;       // 1600 alia slots

// workspace layout (in floats)
constexpr size_t OFF_QEMB = 0;                               // NQ*E
constexpr size_t OFF_AEMB = OFF_QEMB + (size_t)NQ * E;       // NA*E
constexpr size_t OFF_QW2  = OFF_AEMB + (size_t)NA * E;       // NQ
constexpr size_t OFF_AW1  = OFF_QW2 + NQ;                    // NA
constexpr size_t OFF_ATT  = OFF_AW1 + NA;                    // NA*QL
constexpr size_t OFF_ALIG = OFF_ATT + (size_t)NA * QL;       // NA*E
constexpr size_t OFF_CMP  = OFF_ALIG + (size_t)NA * E;       // B*TN*H

// ---------------------------------------------------------------------------
// K1: gather + L2-normalize needed embedding rows; fuse dot with W1/W2.
// grid = NQ + NA blocks, 256 threads.
// ---------------------------------------------------------------------------
__global__ __launch_bounds__(256) void k1_normalize(
    const int* __restrict__ q, const int* __restrict__ alia,
    const float* __restrict__ emb, const float* __restrict__ sim_w,
    float* __restrict__ ws) {
  int slot = blockIdx.x;
  int tid = threadIdx.x;
  bool is_q = slot < NQ;
  int idx = is_q ? q[slot] : alia[slot - NQ];
  const float* src = emb + (size_t)idx * E;
  const float* W = is_q ? (sim_w + E) : sim_w;   // W2 for q rows, W1 for a rows
  float* dst = ws + (is_q ? (OFF_QEMB + (size_t)slot * E)
                          : (OFF_AEMB + (size_t)(slot - NQ) * E));
  float* dotOut = ws + (is_q ? (OFF_QW2 + slot) : (OFF_AW1 + (slot - NQ)));

  float v0 = src[tid];
  float w0 = W[tid];
  float v1 = 0.f, w1 = 0.f;
  int e1 = tid + 256;
  if (e1 < E) { v1 = src[e1]; w1 = W[e1]; }

  float ss = v0 * v0 + v1 * v1;
  float dw = v0 * w0 + v1 * w1;
  #pragma unroll
  for (int off = 32; off > 0; off >>= 1) {
    ss += __shfl_down(ss, off);
    dw += __shfl_down(dw, off);
  }
  __shared__ float r_ss[4], r_dw[4];
  __shared__ float s_scale;
  int wid = tid >> 6, lane = tid & 63;
  if (lane == 0) { r_ss[wid] = ss; r_dw[wid] = dw; }
  __syncthreads();
  if (tid == 0) {
    float tss = r_ss[0] + r_ss[1] + r_ss[2] + r_ss[3];
    float tdw = r_dw[0] + r_dw[1] + r_dw[2] + r_dw[3];
    float nrm = sqrtf(tss);
    float scale = (idx == 0) ? 0.f : (1.f / fmaxf(nrm, 1e-12f));
    s_scale = scale;
    *dotOut = tdw * scale;
  }
  __syncthreads();
  float sc = s_scale;
  dst[tid] = v0 * sc;
  if (e1 < E) dst[e1] = v1 * sc;
}

// ---------------------------------------------------------------------------
// K2a: per (b,tn): stage q_emb[b] in LDS once; 10 rows (one per wave, 3 iters)
// of {atten dots, softmax, alig}. grid = B*TN = 160 blocks, 256 threads.
// ---------------------------------------------------------------------------
__global__ __launch_bounds__(256) void k2a_atten(
    const int* __restrict__ q, const int* __restrict__ alia,
    const float* __restrict__ sim_w, const float* __restrict__ sim_b,
    float* __restrict__ ws) {
  int blk = blockIdx.x;
  int b = blk / TN, tn = blk % TN;
  int tid = threadIdx.x, wid = tid >> 6, lane = tid & 63;

  __shared__ float sq[QL * 301];      // padded stride 301: conflict-free
  __shared__ float s_a3[4][304];
  __shared__ float s_att[4][QL];
  __shared__ float s_p[4][QL];

  const float* qbase = ws + OFF_QEMB + (size_t)b * QL * E;
  for (int i = tid; i < QL * E; i += 256) {
    int r = i / E, e = i - r * E;
    sq[r * 301 + e] = qbase[i];
  }
  float simb = sim_b[0];
  const float* W3 = sim_w + 2 * E;
  __syncthreads();

  for (int it = 0; it < 3; ++it) {
    int m = it * 4 + wid;
    bool valid = m < AL;
    int bm = b * M + tn * AL + m;
    if (valid) {
      const float* arow = ws + OFF_AEMB + (size_t)bm * E;
      for (int e = lane; e < E; e += 64) s_a3[wid][e] = arow[e] * W3[e];
    }
    __syncthreads();
    if (valid) {
      int g = lane >> 1, l = lane & 1;
      const float* qr = &sq[g * 301];
      float part = 0.f;
      for (int e = l; e < E; e += 2) part += s_a3[wid][e] * qr[e];
      part += __shfl_down(part, 1);
      if (l == 0) {
        float att = ws[OFF_AW1 + bm] + ws[OFF_QW2 + b * QL + g] + part + simb;
        if (!(alia[bm] != 0 && q[b * QL + g] != 0)) att = NEGV;
        s_att[wid][g] = att;
        ws[OFF_ATT + (size_t)bm * QL + g] = att;   // for max_atten later
      }
    }
    __syncthreads();
    if (valid) {
      float mx = -INFINITY;
      #pragma unroll
      for (int j = 0; j < QL; j++) mx = fmaxf(mx, s_att[wid][j]);
      float sum = 0.f;
      #pragma unroll
      for (int j = 0; j < QL; j++) sum += expf(s_att[wid][j] - mx);
      if (lane < QL) s_p[wid][lane] = expf(s_att[wid][lane] - mx) / sum;
    }
    __syncthreads();
    if (valid) {
      float* alig = ws + OFF_ALIG + (size_t)bm * E;
      for (int e = lane; e < E; e += 64) {
        float acc = 0.f;
        #pragma unroll
        for (int j = 0; j < QL; j++) acc += s_p[wid][j] * sq[j * 301 + e];
        alig[e] = acc;
      }
    }
    __syncthreads();
  }
}

// ---------------------------------------------------------------------------
// K2b: enc GEMM + relu + sum over al. grid = B*TN*2 = 320 blocks (b,tn,nhalf),
// 256 threads: c = tid&127 (col within half), kh = tid>>7 (K-split:
// kh=0 -> alig x W[:300], kh=1 -> aemb x W[300:]). A rows staged in LDS.
// ---------------------------------------------------------------------------
__global__ __launch_bounds__(256) void k2b_enc(
    const float* __restrict__ enc_w, const float* __restrict__ enc_b,
    float* __restrict__ ws) {
  int blk = blockIdx.x;
  int nh = blk & 1;
  int btn = blk >> 1;             // b*TN + tn
  int tid = threadIdx.x;
  int c = tid & 127, kh = tid >> 7;
  int col = nh * 128 + c;
  int bm0 = btn * AL;             // = b*M + tn*AL

  __shared__ float sA[2 * AL * E];       // [kh][j][e], 24 KB
  __shared__ float s_part[AL][128];      // kh=1 partials, 5 KB

  const float* gA = ws + OFF_ALIG + (size_t)bm0 * E;
  const float* gB = ws + OFF_AEMB + (size_t)bm0 * E;
  for (int i = tid; i < AL * E; i += 256) {
    sA[i] = gA[i];
    sA[AL * E + i] = gB[i];
  }
  __syncthreads();

  const float* __restrict__ wb = enc_w + (size_t)(kh * E) * H + col;
  const float* a = &sA[kh * AL * E];
  float acc[AL] = {0.f, 0.f, 0.f, 0.f, 0.f, 0.f, 0.f, 0.f, 0.f, 0.f};
  #pragma unroll 4
  for (int e = 0; e < E; e++) {
    float w = wb[(size_t)e * H];
    #pragma unroll
    for (int j = 0; j < AL; j++) acc[j] += a[j * E + e] * w;
  }
  if (kh == 1) {
    #pragma unroll
    for (int j = 0; j < AL; j++) s_part[j][c] = acc[j];
  }
  __syncthreads();
  if (kh == 0) {
    float bias = enc_b[col];
    float s = 0.f;
    #pragma unroll
    for (int j = 0; j < AL; j++) s += fmaxf(acc[j] + s_part[j][c] + bias, 0.f);
    ws[OFF_CMP + (size_t)btn * H + col] = s;
  }
}

// ---------------------------------------------------------------------------
// K3: per-b epilogue. grid = B blocks, 640 threads (wave w = tn).
// ---------------------------------------------------------------------------
__global__ __launch_bounds__(640) void k3_final(
    const float* __restrict__ els, const float* __restrict__ elo,
    const float* __restrict__ cate,
    const float* __restrict__ qlin_w, const float* __restrict__ qlin_b,
    const float* __restrict__ cls_w, const float* __restrict__ cls_b,
    const float* __restrict__ ws, float* __restrict__ out) {
  int b = blockIdx.x;
  int tid = threadIdx.x;
  int wid = tid >> 6, lane = tid & 63;
  __shared__ float s_logit[TN], s_p[TN];
  __shared__ float s_at[M * QL];        // 12.8 KB atten block for this b

  const float* attb = ws + OFF_ATT + (size_t)b * M * QL;
  for (int i = tid; i < M * QL; i += 640) s_at[i] = attb[i];

  int tn = wid;
  if (tn < TN) {
    const float* cmp = ws + OFF_CMP + (size_t)(b * TN + tn) * H;
    float v = 0.f;
    #pragma unroll
    for (int k = 0; k < 4; k++) {
      int h = lane + k * 64;
      v += cmp[h] * qlin_w[h];
    }
    #pragma unroll
    for (int off = 32; off > 0; off >>= 1) v += __shfl_down(v, off);
    if (lane == 0) {
      float score = v + qlin_b[0];
      float lo = elo[b * TN + tn], ls = els[b * TN + tn];
      float c0 = cate[(b * TN + tn) * 2 + 0];
      float c1 = cate[(b * TN + tn) * 2 + 1];
      float logit = lo * cls_w[0] + ls * cls_w[1] + c0 * cls_w[2] +
                    c1 * cls_w[3] + score * cls_w[4] + cls_b[0];
      bool tm = (ls + lo) != 0.0f;
      s_logit[tn] = tm ? logit : NEGV;
    }
  }
  __syncthreads();

  if (tid == 0) {
    float mx = -INFINITY;
    for (int t = 0; t < TN; t++) mx = fmaxf(mx, s_logit[t]);
    float sm = 0.f;
    for (int t = 0; t < TN; t++) sm += expf(s_logit[t] - mx);
    for (int t = 0; t < TN; t++) s_p[t] = expf(s_logit[t] - mx) / sm;
  }
  if (tid < TN) out[b * TN + tid] = s_logit[tid];
  __syncthreads();

  if (tid < QL) {
    float sacc = 0.f;
    for (int tn2 = 0; tn2 < TN; tn2++) {
      float mxa = -INFINITY;
      #pragma unroll
      for (int al = 0; al < AL; al++) {
        mxa = fmaxf(mxa, s_at[(tn2 * AL + al) * QL + tid]);
      }
      sacc += s_p[tn2] * mxa;
    }
    float mx = sacc;
    #pragma unroll
    for (int off = 16; off > 0; off >>= 1) mx = fmaxf(mx, __shfl_xor(mx, off, 32));
    float ex = expf(sacc - mx);
    float sm = ex;
    #pragma unroll
    for (int off = 16; off > 0; off >>= 1) sm += __shfl_xor(sm, off, 32);
    out[B * TN + b * QL + tid] = ex / sm;
  }
}

// ---------------------------------------------------------------------------
extern "C" void kernel_launch(void* const* d_in, const int* in_sizes, int n_in,
                              void* d_out, int out_size, void* d_ws, size_t ws_size,
                              hipStream_t stream) {
  const int*   q      = (const int*)  d_in[0];
  const int*   alia   = (const int*)  d_in[1];
  const float* els    = (const float*)d_in[2];
  const float* elo    = (const float*)d_in[3];
  const float* cate   = (const float*)d_in[4];
  const float* emb    = (const float*)d_in[5];
  const float* sim_w  = (const float*)d_in[6];
  const float* sim_b  = (const float*)d_in[7];
  const float* enc_w  = (const float*)d_in[8];
  const float* enc_b  = (const float*)d_in[9];
  const float* qlin_w = (const float*)d_in[10];
  const float* qlin_b = (const float*)d_in[11];
  const float* cls_w  = (const float*)d_in[12];
  const float* cls_b  = (const float*)d_in[13];
  float* out = (float*)d_out;
  float* ws  = (float*)d_ws;

  k1_normalize<<<NQ + NA, 256, 0, stream>>>(q, alia, emb, sim_w, ws);
  k2a_atten<<<B * TN, 256, 0, stream>>>(q, alia, sim_w, sim_b, ws);
  k2b_enc<<<B * TN * 2, 256, 0, stream>>>(enc_w, enc_b, ws);
  k3_final<<<B, 640, 0, stream>>>(els, elo, cate, qlin_w, qlin_b, cls_w, cls_b,
                                  ws, out);
}

// Round 3
// 63.746 us; speedup vs baseline: 1.2759x; 1.1320x over previous
//
#include <hip/hip_runtime.h>
#include <math.h>

#define NEGV (-10000000000.0f)

constexpr int B  = 16;
constexpr int QL = 32;
constexpr int TN = 10;
constexpr int AL = 10;
constexpr int E  = 300;
constexpr int H  = 256;
constexpr int M  = TN * AL;     // 100
constexpr int NQ = B * QL;      // 512 q slots
constexpr int NA = B * M;      // 1600 alia slots

// workspace layout (in floats)
constexpr size_t OFF_QEMB = 0;                               // NQ*E
constexpr size_t OFF_AEMB = OFF_QEMB + (size_t)NQ * E;       // NA*E
constexpr size_t OFF_QW2  = OFF_AEMB + (size_t)NA * E;       // NQ
constexpr size_t OFF_AW1  = OFF_QW2 + NQ;                    // NA
constexpr size_t OFF_ATT  = OFF_AW1 + NA;                    // NA*QL
constexpr size_t OFF_ALIG = OFF_ATT + (size_t)NA * QL;       // NA*E
constexpr size_t OFF_CMP  = OFF_ALIG + (size_t)NA * E;       // B*TN*2*H (j-half split)

// ---------------------------------------------------------------------------
// K1: gather + L2-normalize needed embedding rows; fuse dot with W1/W2.
// grid = NQ + NA blocks, 256 threads.
// ---------------------------------------------------------------------------
__global__ __launch_bounds__(256) void k1_normalize(
    const int* __restrict__ q, const int* __restrict__ alia,
    const float* __restrict__ emb, const float* __restrict__ sim_w,
    float* __restrict__ ws) {
  int slot = blockIdx.x;
  int tid = threadIdx.x;
  bool is_q = slot < NQ;
  int idx = is_q ? q[slot] : alia[slot - NQ];
  const float* src = emb + (size_t)idx * E;
  const float* W = is_q ? (sim_w + E) : sim_w;   // W2 for q rows, W1 for a rows
  float* dst = ws + (is_q ? (OFF_QEMB + (size_t)slot * E)
                          : (OFF_AEMB + (size_t)(slot - NQ) * E));
  float* dotOut = ws + (is_q ? (OFF_QW2 + slot) : (OFF_AW1 + (slot - NQ)));

  float v0 = src[tid];
  float w0 = W[tid];
  float v1 = 0.f, w1 = 0.f;
  int e1 = tid + 256;
  if (e1 < E) { v1 = src[e1]; w1 = W[e1]; }

  float ss = v0 * v0 + v1 * v1;
  float dw = v0 * w0 + v1 * w1;
  #pragma unroll
  for (int off = 32; off > 0; off >>= 1) {
    ss += __shfl_down(ss, off);
    dw += __shfl_down(dw, off);
  }
  __shared__ float r_ss[4], r_dw[4];
  __shared__ float s_scale;
  int wid = tid >> 6, lane = tid & 63;
  if (lane == 0) { r_ss[wid] = ss; r_dw[wid] = dw; }
  __syncthreads();
  if (tid == 0) {
    float tss = r_ss[0] + r_ss[1] + r_ss[2] + r_ss[3];
    float tdw = r_dw[0] + r_dw[1] + r_dw[2] + r_dw[3];
    float nrm = sqrtf(tss);
    float scale = (idx == 0) ? 0.f : (1.f / fmaxf(nrm, 1e-12f));
    s_scale = scale;
    *dotOut = tdw * scale;
  }
  __syncthreads();
  float sc = s_scale;
  dst[tid] = v0 * sc;
  if (e1 < E) dst[e1] = v1 * sc;
}

// ---------------------------------------------------------------------------
// K2a: per (b,tn): stage q_emb[b] in LDS once; 10 rows (one per wave, 3 iters)
// of {atten dots, softmax, alig}. grid = B*TN = 160 blocks, 256 threads.
// ---------------------------------------------------------------------------
__global__ __launch_bounds__(256) void k2a_atten(
    const int* __restrict__ q, const int* __restrict__ alia,
    const float* __restrict__ sim_w, const float* __restrict__ sim_b,
    float* __restrict__ ws) {
  int blk = blockIdx.x;
  int b = blk / TN, tn = blk % TN;
  int tid = threadIdx.x, wid = tid >> 6, lane = tid & 63;

  __shared__ float sq[QL * 301];      // padded stride 301: conflict-free
  __shared__ float s_a3[4][304];
  __shared__ float s_att[4][QL];
  __shared__ float s_p[4][QL];

  const float* qbase = ws + OFF_QEMB + (size_t)b * QL * E;
  for (int i = tid; i < QL * E; i += 256) {
    int r = i / E, e = i - r * E;
    sq[r * 301 + e] = qbase[i];
  }
  float simb = sim_b[0];
  const float* W3 = sim_w + 2 * E;
  __syncthreads();

  for (int it = 0; it < 3; ++it) {
    int m = it * 4 + wid;
    bool valid = m < AL;
    int bm = b * M + tn * AL + m;
    if (valid) {
      const float* arow = ws + OFF_AEMB + (size_t)bm * E;
      for (int e = lane; e < E; e += 64) s_a3[wid][e] = arow[e] * W3[e];
    }
    __syncthreads();
    if (valid) {
      int g = lane >> 1, l = lane & 1;
      const float* qr = &sq[g * 301];
      float part = 0.f;
      for (int e = l; e < E; e += 2) part += s_a3[wid][e] * qr[e];
      part += __shfl_down(part, 1);
      if (l == 0) {
        float att = ws[OFF_AW1 + bm] + ws[OFF_QW2 + b * QL + g] + part + simb;
        if (!(alia[bm] != 0 && q[b * QL + g] != 0)) att = NEGV;
        s_att[wid][g] = att;
        ws[OFF_ATT + (size_t)bm * QL + g] = att;   // for max_atten later
      }
    }
    __syncthreads();
    if (valid) {
      float mx = -INFINITY;
      #pragma unroll
      for (int j = 0; j < QL; j++) mx = fmaxf(mx, s_att[wid][j]);
      float sum = 0.f;
      #pragma unroll
      for (int j = 0; j < QL; j++) sum += expf(s_att[wid][j] - mx);
      if (lane < QL) s_p[wid][lane] = expf(s_att[wid][lane] - mx) / sum;
    }
    __syncthreads();
    if (valid) {
      float* alig = ws + OFF_ALIG + (size_t)bm * E;
      for (int e = lane; e < E; e += 64) {
        float acc = 0.f;
        #pragma unroll
        for (int j = 0; j < QL; j++) acc += s_p[wid][j] * sq[j * 301 + e];
        alig[e] = acc;
      }
    }
    __syncthreads();
  }
}

// ---------------------------------------------------------------------------
// K2b: enc GEMM + relu + sum over j-half.
// grid = 640 blocks: blk = ((btn*2 + jh)*2 + nh); btn=(b,tn), jh=row-half
// (5 rows), nh=col-half (128 cols).
// threads 256 = c(32) x kq(8). Thread computes cols col=nh*128+c+nc*32,
// nc=0..3, over K-slice kq. A (5x600) staged in LDS; per-chunk: 5 ds_read_b128
// feed 80 FMAs. Partials reduced via LDS; relu+sum over 5 rows ->
// cmp[(btn*2+jh)*H + col].
// ---------------------------------------------------------------------------
__global__ __launch_bounds__(256) void k2b_enc(
    const float* __restrict__ enc_w, const float* __restrict__ enc_b,
    float* __restrict__ ws) {
  int blk = blockIdx.x;
  int nh = blk & 1;
  int jh = (blk >> 1) & 1;
  int btn = blk >> 2;             // b*TN + tn
  int tid = threadIdx.x;
  int c = tid & 31, kq = tid >> 5;
  int bm0 = btn * AL + jh * 5;

  __shared__ float sA[5 * 600];          // [j][k], k<300: alig, k>=300: aemb
  __shared__ float spart[8 * 5 * 4 * 32]; // [kq][j][nc][c]

  const float* gA = ws + OFF_ALIG + (size_t)bm0 * E;
  const float* gB = ws + OFF_AEMB + (size_t)bm0 * E;
  for (int i = tid; i < 5 * 600; i += 256) {
    int j = i / 600, k = i - j * 600;
    sA[i] = (k < E) ? gA[(size_t)j * E + k] : gB[(size_t)j * E + (k - E)];
  }
  __syncthreads();

  int ks = kq * 76;
  int klen = (kq == 7) ? 68 : 76;

  float acc[5][4] = {};
  for (int ch = 0; ch < klen; ch += 4) {
    int k = ks + ch;
    float4 a[5];
    #pragma unroll
    for (int j = 0; j < 5; j++) a[j] = *(const float4*)&sA[j * 600 + k];
    const float* __restrict__ wp = enc_w + (size_t)k * H + nh * 128 + c;
    #pragma unroll
    for (int e = 0; e < 4; e++) {
      float w0 = wp[e * H + 0];
      float w1 = wp[e * H + 32];
      float w2 = wp[e * H + 64];
      float w3 = wp[e * H + 96];
      #pragma unroll
      for (int j = 0; j < 5; j++) {
        float av = (e == 0) ? a[j].x : (e == 1) ? a[j].y : (e == 2) ? a[j].z : a[j].w;
        acc[j][0] += av * w0;
        acc[j][1] += av * w1;
        acc[j][2] += av * w2;
        acc[j][3] += av * w3;
      }
    }
  }

  // write partials: spart[kq][j][nc][c]
  #pragma unroll
  for (int j = 0; j < 5; j++)
    #pragma unroll
    for (int nc = 0; nc < 4; nc++)
      spart[((kq * 5 + j) * 4 + nc) * 32 + c] = acc[j][nc];
  __syncthreads();

  // final: 128 threads, one col each: sum 8 kq partials, +bias, relu, sum 5 rows
  if (tid < 128) {
    int colh = tid;               // nc*32 + c
    int col = nh * 128 + colh;
    float bias = enc_b[col];
    float s = 0.f;
    #pragma unroll
    for (int j = 0; j < 5; j++) {
      float v = bias;
      #pragma unroll
      for (int kk = 0; kk < 8; kk++)
        v += spart[((kk * 5 + j) * 4) * 32 + colh];
      s += fmaxf(v, 0.f);
    }
    ws[OFF_CMP + (size_t)(btn * 2 + jh) * H + col] = s;
  }
}

// ---------------------------------------------------------------------------
// K3: per-b epilogue. grid = B blocks, 640 threads (wave w = tn).
// ---------------------------------------------------------------------------
__global__ __launch_bounds__(640) void k3_final(
    const float* __restrict__ els, const float* __restrict__ elo,
    const float* __restrict__ cate,
    const float* __restrict__ qlin_w, const float* __restrict__ qlin_b,
    const float* __restrict__ cls_w, const float* __restrict__ cls_b,
    const float* __restrict__ ws, float* __restrict__ out) {
  int b = blockIdx.x;
  int tid = threadIdx.x;
  int wid = tid >> 6, lane = tid & 63;
  __shared__ float s_logit[TN], s_p[TN];
  __shared__ float s_at[M * QL];        // 12.8 KB atten block for this b

  const float* attb = ws + OFF_ATT + (size_t)b * M * QL;
  for (int i = tid; i < M * QL; i += 640) s_at[i] = attb[i];

  int tn = wid;
  if (tn < TN) {
    const float* cmp = ws + OFF_CMP + (size_t)(b * TN + tn) * 2 * H;
    float v = 0.f;
    #pragma unroll
    for (int k = 0; k < 4; k++) {
      int h = lane + k * 64;
      v += (cmp[h] + cmp[H + h]) * qlin_w[h];
    }
    #pragma unroll
    for (int off = 32; off > 0; off >>= 1) v += __shfl_down(v, off);
    if (lane == 0) {
      float score = v + qlin_b[0];
      float lo = elo[b * TN + tn], ls = els[b * TN + tn];
      float c0 = cate[(b * TN + tn) * 2 + 0];
      float c1 = cate[(b * TN + tn) * 2 + 1];
      float logit = lo * cls_w[0] + ls * cls_w[1] + c0 * cls_w[2] +
                    c1 * cls_w[3] + score * cls_w[4] + cls_b[0];
      bool tm = (ls + lo) != 0.0f;
      s_logit[tn] = tm ? logit : NEGV;
    }
  }
  __syncthreads();

  if (tid == 0) {
    float mx = -INFINITY;
    for (int t = 0; t < TN; t++) mx = fmaxf(mx, s_logit[t]);
    float sm = 0.f;
    for (int t = 0; t < TN; t++) sm += expf(s_logit[t] - mx);
    for (int t = 0; t < TN; t++) s_p[t] = expf(s_logit[t] - mx) / sm;
  }
  if (tid < TN) out[b * TN + tid] = s_logit[tid];
  __syncthreads();

  if (tid < QL) {
    float sacc = 0.f;
    for (int tn2 = 0; tn2 < TN; tn2++) {
      float mxa = -INFINITY;
      #pragma unroll
      for (int al = 0; al < AL; al++) {
        mxa = fmaxf(mxa, s_at[(tn2 * AL + al) * QL + tid]);
      }
      sacc += s_p[tn2] * mxa;
    }
    float mx = sacc;
    #pragma unroll
    for (int off = 16; off > 0; off >>= 1) mx = fmaxf(mx, __shfl_xor(mx, off, 32));
    float ex = expf(sacc - mx);
    float sm = ex;
    #pragma unroll
    for (int off = 16; off > 0; off >>= 1) sm += __shfl_xor(sm, off, 32);
    out[B * TN + b * QL + tid] = ex / sm;
  }
}

// ---------------------------------------------------------------------------
extern "C" void kernel_launch(void* const* d_in, const int* in_sizes, int n_in,
                              void* d_out, int out_size, void* d_ws, size_t ws_size,
                              hipStream_t stream) {
  const int*   q      = (const int*)  d_in[0];
  const int*   alia   = (const int*)  d_in[1];
  const float* els    = (const float*)d_in[2];
  const float* elo    = (const float*)d_in[3];
  const float* cate   = (const float*)d_in[4];
  const float* emb    = (const float*)d_in[5];
  const float* sim_w  = (const float*)d_in[6];
  const float* sim_b  = (const float*)d_in[7];
  const float* enc_w  = (const float*)d_in[8];
  const float* enc_b  = (const float*)d_in[9];
  const float* qlin_w = (const float*)d_in[10];
  const float* qlin_b = (const float*)d_in[11];
  const float* cls_w  = (const float*)d_in[12];
  const float* cls_b  = (const float*)d_in[13];
  float* out = (float*)d_out;
  float* ws  = (float*)d_ws;

  k1_normalize<<<NQ + NA, 256, 0, stream>>>(q, alia, emb, sim_w, ws);
  k2a_atten<<<B * TN, 256, 0, stream>>>(q, alia, sim_w, sim_b, ws);
  k2b_enc<<<B * TN * 4, 256, 0, stream>>>(enc_w, enc_b, ws);
  k3_final<<<B, 640, 0, stream>>>(els, elo, cate, qlin_w, qlin_b, cls_w, cls_b,
                                  ws, out);
}

// Round 4
// 40.621 us; speedup vs baseline: 2.0023x; 1.5693x over previous
//
#include <hip/hip_runtime.h>
#include <math.h>

#define NEGV (-10000000000.0f)

constexpr int B  = 16;
constexpr int QL = 32;
constexpr int TN = 10;
constexpr int AL = 10;
constexpr int E  = 300;
constexpr int H  = 256;
constexpr int M  = TN * AL;     // 100
constexpr int NQ = B * QL;      // 512 q slots
constexpr int NA = B * M;       // 1600 alia slots
constexpr int SQS = 304;        // padded row stride for gathered embeddings

// workspace layout (in floats)
constexpr size_t OFF_QEMB = 0;                                 // NQ*SQS
constexpr size_t OFF_AEMB = OFF_QEMB + (size_t)NQ * SQS;       // NA*SQS
constexpr size_t OFF_QW2  = OFF_AEMB + (size_t)NA * SQS;       // NQ
constexpr size_t OFF_AW1  = OFF_QW2 + NQ;                      // NA
constexpr size_t OFF_ATT  = OFF_AW1 + NA;                      // NA*QL
constexpr size_t OFF_P    = OFF_ATT + (size_t)NA * QL;         // NA*QL
constexpr size_t OFF_QW   = OFF_P + (size_t)NA * QL;           // NQ*H
constexpr size_t OFF_CMP  = OFF_QW + (size_t)NQ * H;           // B*TN*2*H

// ---------------------------------------------------------------------------
// K1: gather + L2-normalize needed embedding rows (padded stride SQS, zero
// pad) and fuse the dot with W1/W2. grid = NQ + NA blocks, 256 threads.
// ---------------------------------------------------------------------------
__global__ __launch_bounds__(256) void k1_normalize(
    const int* __restrict__ q, const int* __restrict__ alia,
    const float* __restrict__ emb, const float* __restrict__ sim_w,
    float* __restrict__ ws) {
  int slot = blockIdx.x;
  int tid = threadIdx.x;
  bool is_q = slot < NQ;
  int idx = is_q ? q[slot] : alia[slot - NQ];
  const float* src = emb + (size_t)idx * E;
  const float* W = is_q ? (sim_w + E) : sim_w;   // W2 for q rows, W1 for a rows
  float* dst = ws + (is_q ? (OFF_QEMB + (size_t)slot * SQS)
                          : (OFF_AEMB + (size_t)(slot - NQ) * SQS));
  float* dotOut = ws + (is_q ? (OFF_QW2 + slot) : (OFF_AW1 + (slot - NQ)));

  float v0 = src[tid];
  float w0 = W[tid];
  float v1 = 0.f, w1 = 0.f;
  int e1 = tid + 256;
  if (e1 < E) { v1 = src[e1]; w1 = W[e1]; }

  float ss = v0 * v0 + v1 * v1;
  float dw = v0 * w0 + v1 * w1;
  #pragma unroll
  for (int off = 32; off > 0; off >>= 1) {
    ss += __shfl_down(ss, off);
    dw += __shfl_down(dw, off);
  }
  __shared__ float r_ss[4], r_dw[4];
  __shared__ float s_scale;
  int wid = tid >> 6, lane = tid & 63;
  if (lane == 0) { r_ss[wid] = ss; r_dw[wid] = dw; }
  __syncthreads();
  if (tid == 0) {
    float tss = r_ss[0] + r_ss[1] + r_ss[2] + r_ss[3];
    float tdw = r_dw[0] + r_dw[1] + r_dw[2] + r_dw[3];
    float nrm = sqrtf(tss);
    float scale = (idx == 0) ? 0.f : (1.f / fmaxf(nrm, 1e-12f));
    s_scale = scale;
    *dotOut = tdw * scale;
  }
  __syncthreads();
  float sc = s_scale;
  dst[tid] = v0 * sc;
  if (e1 < E) dst[e1] = v1 * sc;
  else if (e1 < SQS) dst[e1] = 0.f;     // zero pad 300..303
}

// ---------------------------------------------------------------------------
// K2 fused, 288 blocks:
//  role A (blk < 160): per (b,tn) atten + softmax -> P  (no alig!)
//  role B (blk >= 160): QW = Qemb @ enc_w[:300]  (64 rowgroups x 2 col-halves)
// ---------------------------------------------------------------------------
__global__ __launch_bounds__(256) void k2_fused(
    const int* __restrict__ q, const int* __restrict__ alia,
    const float* __restrict__ sim_w, const float* __restrict__ sim_b,
    const float* __restrict__ enc_w, float* __restrict__ ws) {
  __shared__ float smem[32 * 308 + 4 * 304 + 4 * 32];   // 11200 floats, 44.8 KB
  int tid = threadIdx.x;

  if (blockIdx.x < 160) {
    // ---- role A: attention ----
    int b = blockIdx.x / TN, tn = blockIdx.x % TN;
    int wid = tid >> 6, lane = tid & 63;
    float* sq    = smem;                       // [32][308]
    float* a3    = smem + 32 * 308;            // [4][304]
    float* s_att = smem + 32 * 308 + 4 * 304;  // [4][32]

    const float* qb = ws + OFF_QEMB + (size_t)b * QL * SQS;
    for (int i = tid; i < QL * 76; i += 256) {
      int r = i / 76, e4 = i % 76;
      *(float4*)&sq[r * 308 + e4 * 4] = *(const float4*)&qb[r * SQS + e4 * 4];
    }
    float simb = sim_b[0];
    const float* w3 = sim_w + 2 * E;
    __syncthreads();

    for (int it = 0; it < 3; ++it) {
      int m = it * 4 + wid;
      bool valid = m < AL;
      int bm = (b * TN + tn) * AL + m;
      if (valid) {
        const float* ar = ws + OFF_AEMB + (size_t)bm * SQS;
        for (int e4 = lane; e4 < 75; e4 += 64) {
          float4 av = *(const float4*)&ar[e4 * 4];
          float4 wv = *(const float4*)&w3[e4 * 4];
          float4 r;
          r.x = av.x * wv.x; r.y = av.y * wv.y;
          r.z = av.z * wv.z; r.w = av.w * wv.w;
          *(float4*)&a3[wid * 304 + e4 * 4] = r;
        }
      }
      __syncthreads();
      if (valid) {
        int g = lane >> 1, l = lane & 1;
        const float* qr = &sq[g * 308];
        const float* ap = &a3[wid * 304];
        float part = 0.f;
        int e4b = l ? 38 : 0, e4e = l ? 75 : 38;
        for (int e4 = e4b; e4 < e4e; ++e4) {
          float4 av = *(const float4*)&ap[e4 * 4];
          float4 qv = *(const float4*)&qr[e4 * 4];
          part += av.x * qv.x + av.y * qv.y + av.z * qv.z + av.w * qv.w;
        }
        part += __shfl_down(part, 1);
        if (l == 0) {
          float att = ws[OFF_AW1 + bm] + ws[OFF_QW2 + b * QL + g] + part + simb;
          if (!(alia[bm] != 0 && q[b * QL + g] != 0)) att = NEGV;
          s_att[wid * 32 + g] = att;
          ws[OFF_ATT + (size_t)bm * QL + g] = att;   // for max_atten in k3
        }
      }
      __syncthreads();
      if (valid) {
        float mx = -INFINITY;
        #pragma unroll
        for (int j = 0; j < QL; j++) mx = fmaxf(mx, s_att[wid * 32 + j]);
        float sum = 0.f;
        #pragma unroll
        for (int j = 0; j < QL; j++) sum += expf(s_att[wid * 32 + j] - mx);
        if (lane < QL)
          ws[OFF_P + (size_t)bm * QL + lane] =
              expf(s_att[wid * 32 + lane] - mx) / sum;
      }
      __syncthreads();
    }
  } else {
    // ---- role B: QW GEMM (512 x 300 @ 300 x 256) ----
    int rg = blockIdx.x - 160;
    int nh = rg & 1, rgi = rg >> 1;     // 64 rowgroups of 8 q-slots
    int slot0 = rgi * 8;
    float* sQ = smem;                   // [8][304]
    float* spart = smem + 8 * 304;      // [8kq][8j][4nc][32c] = 8192

    const float* qb = ws + OFF_QEMB + (size_t)slot0 * SQS;
    for (int i = tid; i < 8 * 76; i += 256) {
      int r = i / 76, e4 = i % 76;
      *(float4*)&sQ[r * 304 + e4 * 4] = *(const float4*)&qb[r * SQS + e4 * 4];
    }
    __syncthreads();

    int c = tid & 31, kq = tid >> 5;
    int ks = kq * 40;
    int nch = (kq == 7) ? 5 : 10;       // 7*40 + 20 = 300
    float acc[8][4] = {};
    for (int ch = 0; ch < nch; ++ch) {
      int k = ks + ch * 4;
      float4 a[8];
      #pragma unroll
      for (int j = 0; j < 8; j++) a[j] = *(const float4*)&sQ[j * 304 + k];
      const float* wp = enc_w + (size_t)k * H + nh * 128 + c;
      #pragma unroll
      for (int e = 0; e < 4; e++) {
        float w0 = wp[e * H + 0];
        float w1 = wp[e * H + 32];
        float w2 = wp[e * H + 64];
        float w3v = wp[e * H + 96];
        #pragma unroll
        for (int j = 0; j < 8; j++) {
          float av = (e == 0) ? a[j].x : (e == 1) ? a[j].y
                   : (e == 2) ? a[j].z : a[j].w;
          acc[j][0] += av * w0; acc[j][1] += av * w1;
          acc[j][2] += av * w2; acc[j][3] += av * w3v;
        }
      }
    }
    #pragma unroll
    for (int j = 0; j < 8; j++)
      #pragma unroll
      for (int nc = 0; nc < 4; nc++)
        spart[((kq * 8 + j) * 4 + nc) * 32 + c] = acc[j][nc];
    __syncthreads();
    #pragma unroll
    for (int t = 0; t < 4; t++) {
      int o = tid + t * 256;
      int j = o >> 7, colh = o & 127;
      float s = 0.f;
      #pragma unroll
      for (int kk = 0; kk < 8; kk++)
        s += spart[((kk * 8 + j) * 4 + (colh >> 5)) * 32 + (colh & 31)];
      ws[OFF_QW + (size_t)(slot0 + j) * H + nh * 128 + colh] = s;
    }
  }
}

// ---------------------------------------------------------------------------
// K2b: enc = relu(P@QW + aemb@W2 + bias), summed over 5-row half.
// grid = 640 blocks (btn, jh, nh), 256 threads = 32c x 8kq.
// Each kq slice: 4 P-k's (via QW) + ~40 aemb-k's.
// ---------------------------------------------------------------------------
__global__ __launch_bounds__(256) void k2b_enc(
    const float* __restrict__ enc_w, const float* __restrict__ enc_b,
    float* __restrict__ ws) {
  int blk = blockIdx.x;
  int nh = blk & 1, jh = (blk >> 1) & 1, btn = blk >> 2;
  int b = btn / TN;
  int tid = threadIdx.x;
  int c = tid & 31, kq = tid >> 5;
  int bm0 = btn * AL + jh * 5;

  __shared__ float sA[5 * 304];
  __shared__ float sP[5 * 32];
  __shared__ float spart[8 * 5 * 4 * 32];

  const float* ga = ws + OFF_AEMB + (size_t)bm0 * SQS;
  for (int i = tid; i < 5 * 76; i += 256) {
    int j = i / 76, e4 = i % 76;
    *(float4*)&sA[j * 304 + e4 * 4] = *(const float4*)&ga[j * SQS + e4 * 4];
  }
  if (tid < 160) sP[tid] = ws[OFF_P + (size_t)bm0 * QL + tid];
  __syncthreads();

  float acc[5][4] = {};

  // ---- P @ QW part: this kq handles pk = kq*4 .. kq*4+3 ----
  {
    float4 pv[5];
    #pragma unroll
    for (int j = 0; j < 5; j++) pv[j] = *(const float4*)&sP[j * 32 + kq * 4];
    const float* qwb = ws + OFF_QW + (size_t)(b * QL + kq * 4) * H + nh * 128 + c;
    #pragma unroll
    for (int pp = 0; pp < 4; pp++) {
      float w0 = qwb[pp * H + 0];
      float w1 = qwb[pp * H + 32];
      float w2 = qwb[pp * H + 64];
      float w3v = qwb[pp * H + 96];
      #pragma unroll
      for (int j = 0; j < 5; j++) {
        float p = (pp == 0) ? pv[j].x : (pp == 1) ? pv[j].y
                : (pp == 2) ? pv[j].z : pv[j].w;
        acc[j][0] += p * w0; acc[j][1] += p * w1;
        acc[j][2] += p * w2; acc[j][3] += p * w3v;
      }
    }
  }

  // ---- aemb @ W2 part ----
  int ks = kq * 40;
  int nch = (kq == 7) ? 5 : 10;         // 7*40 + 20 = 300
  for (int ch = 0; ch < nch; ++ch) {
    int k = ks + ch * 4;
    float4 a[5];
    #pragma unroll
    for (int j = 0; j < 5; j++) a[j] = *(const float4*)&sA[j * 304 + k];
    const float* wp = enc_w + (size_t)(E + k) * H + nh * 128 + c;
    #pragma unroll
    for (int e = 0; e < 4; e++) {
      float w0 = wp[e * H + 0];
      float w1 = wp[e * H + 32];
      float w2 = wp[e * H + 64];
      float w3v = wp[e * H + 96];
      #pragma unroll
      for (int j = 0; j < 5; j++) {
        float av = (e == 0) ? a[j].x : (e == 1) ? a[j].y
                 : (e == 2) ? a[j].z : a[j].w;
        acc[j][0] += av * w0; acc[j][1] += av * w1;
        acc[j][2] += av * w2; acc[j][3] += av * w3v;
      }
    }
  }

  #pragma unroll
  for (int j = 0; j < 5; j++)
    #pragma unroll
    for (int nc = 0; nc < 4; nc++)
      spart[((kq * 5 + j) * 4 + nc) * 32 + c] = acc[j][nc];
  __syncthreads();

  if (tid < 128) {
    int colh = tid, col = nh * 128 + colh;
    float bias = enc_b[col];
    float s = 0.f;
    #pragma unroll
    for (int j = 0; j < 5; j++) {
      float v = bias;
      #pragma unroll
      for (int kk = 0; kk < 8; kk++)
        v += spart[((kk * 5 + j) * 4 + (colh >> 5)) * 32 + (colh & 31)];
      s += fmaxf(v, 0.f);
    }
    ws[OFF_CMP + (size_t)(btn * 2 + jh) * H + col] = s;
  }
}

// ---------------------------------------------------------------------------
// K3: per-b epilogue. grid = B blocks, 640 threads (wave w = tn).
// ---------------------------------------------------------------------------
__global__ __launch_bounds__(640) void k3_final(
    const float* __restrict__ els, const float* __restrict__ elo,
    const float* __restrict__ cate,
    const float* __restrict__ qlin_w, const float* __restrict__ qlin_b,
    const float* __restrict__ cls_w, const float* __restrict__ cls_b,
    const float* __restrict__ ws, float* __restrict__ out) {
  int b = blockIdx.x;
  int tid = threadIdx.x;
  int wid = tid >> 6, lane = tid & 63;
  __shared__ float s_logit[TN], s_p[TN];
  __shared__ float s_at[M * QL];

  const float* attb = ws + OFF_ATT + (size_t)b * M * QL;
  for (int i = tid; i < M * QL; i += 640) s_at[i] = attb[i];

  int tn = wid;
  if (tn < TN) {
    const float* cmp = ws + OFF_CMP + (size_t)(b * TN + tn) * 2 * H;
    float v = 0.f;
    #pragma unroll
    for (int k = 0; k < 4; k++) {
      int h = lane + k * 64;
      v += (cmp[h] + cmp[H + h]) * qlin_w[h];
    }
    #pragma unroll
    for (int off = 32; off > 0; off >>= 1) v += __shfl_down(v, off);
    if (lane == 0) {
      float score = v + qlin_b[0];
      float lo = elo[b * TN + tn], ls = els[b * TN + tn];
      float c0 = cate[(b * TN + tn) * 2 + 0];
      float c1 = cate[(b * TN + tn) * 2 + 1];
      float logit = lo * cls_w[0] + ls * cls_w[1] + c0 * cls_w[2] +
                    c1 * cls_w[3] + score * cls_w[4] + cls_b[0];
      bool tm = (ls + lo) != 0.0f;
      s_logit[tn] = tm ? logit : NEGV;
    }
  }
  __syncthreads();

  if (tid == 0) {
    float mx = -INFINITY;
    for (int t = 0; t < TN; t++) mx = fmaxf(mx, s_logit[t]);
    float sm = 0.f;
    for (int t = 0; t < TN; t++) sm += expf(s_logit[t] - mx);
    for (int t = 0; t < TN; t++) s_p[t] = expf(s_logit[t] - mx) / sm;
  }
  if (tid < TN) out[b * TN + tid] = s_logit[tid];
  __syncthreads();

  if (tid < QL) {
    float sacc = 0.f;
    for (int tn2 = 0; tn2 < TN; tn2++) {
      float mxa = -INFINITY;
      #pragma unroll
      for (int al = 0; al < AL; al++) {
        mxa = fmaxf(mxa, s_at[(tn2 * AL + al) * QL + tid]);
      }
      sacc += s_p[tn2] * mxa;
    }
    float mx = sacc;
    #pragma unroll
    for (int off = 16; off > 0; off >>= 1) mx = fmaxf(mx, __shfl_xor(mx, off, 32));
    float ex = expf(sacc - mx);
    float sm = ex;
    #pragma unroll
    for (int off = 16; off > 0; off >>= 1) sm += __shfl_xor(sm, off, 32);
    out[B * TN + b * QL + tid] = ex / sm;
  }
}

// ---------------------------------------------------------------------------
extern "C" void kernel_launch(void* const* d_in, const int* in_sizes, int n_in,
                              void* d_out, int out_size, void* d_ws, size_t ws_size,
                              hipStream_t stream) {
  const int*   q      = (const int*)  d_in[0];
  const int*   alia   = (const int*)  d_in[1];
  const float* els    = (const float*)d_in[2];
  const float* elo    = (const float*)d_in[3];
  const float* cate   = (const float*)d_in[4];
  const float* emb    = (const float*)d_in[5];
  const float* sim_w  = (const float*)d_in[6];
  const float* sim_b  = (const float*)d_in[7];
  const float* enc_w  = (const float*)d_in[8];
  const float* enc_b  = (const float*)d_in[9];
  const float* qlin_w = (const float*)d_in[10];
  const float* qlin_b = (const float*)d_in[11];
  const float* cls_w  = (const float*)d_in[12];
  const float* cls_b  = (const float*)d_in[13];
  float* out = (float*)d_out;
  float* ws  = (float*)d_ws;

  k1_normalize<<<NQ + NA, 256, 0, stream>>>(q, alia, emb, sim_w, ws);
  k2_fused<<<160 + 128, 256, 0, stream>>>(q, alia, sim_w, sim_b, enc_w, ws);
  k2b_enc<<<B * TN * 4, 256, 0, stream>>>(enc_w, enc_b, ws);
  k3_final<<<B, 640, 0, stream>>>(els, elo, cate, qlin_w, qlin_b, cls_w, cls_b,
                                  ws, out);
}

// Round 5
// 34.928 us; speedup vs baseline: 2.3286x; 1.1630x over previous
//
#include <hip/hip_runtime.h>
#include <math.h>

#define NEGV (-10000000000.0f)

constexpr int B  = 16;
constexpr int QL = 32;
constexpr int TN = 10;
constexpr int AL = 10;
constexpr int E  = 300;
constexpr int H  = 256;
constexpr int M  = TN * AL;     // 100
constexpr int NQ = B * QL;      // 512 q slots
constexpr int NA = B * M;       // 1600 alia slots
constexpr int SQS = 304;        // padded row stride for stored aemb rows

// workspace layout (in floats)
constexpr size_t OFF_AEMB = 0;                                 // NA*SQS
constexpr size_t OFF_ATT  = OFF_AEMB + (size_t)NA * SQS;       // NA*QL
constexpr size_t OFF_P    = OFF_ATT + (size_t)NA * QL;         // NA*QL
constexpr size_t OFF_QW   = OFF_P + (size_t)NA * QL;           // NQ*H
constexpr size_t OFF_PS   = OFF_QW + (size_t)NQ * H;           // 640

// ---------------------------------------------------------------------------
// K2 fused (448 blocks, 256 thr). Gathers + normalizes emb rows itself (k1
// eliminated; scales factor out algebraically).
//  role A (blk < 320): per (b,tn,mh): atten (5 m-rows) + softmax -> ATT, P;
//                      writes normalized aemb rows for k2b.
//  role B (blk >= 320): QW = Qemb_n @ enc_w[:300] (64 rowgroups x 2 halves).
// ---------------------------------------------------------------------------
__global__ __launch_bounds__(256) void k2_fused(
    const int* __restrict__ q, const int* __restrict__ alia,
    const float* __restrict__ emb,
    const float* __restrict__ sim_w, const float* __restrict__ sim_b,
    const float* __restrict__ enc_w, float* __restrict__ ws) {
  __shared__ float smem[13248];      // 53 KB, max(roleA, roleB)
  int tid = threadIdx.x;
  int wid = tid >> 6, lane = tid & 63;

  if (blockIdx.x < 320) {
    // ================= role A =================
    int mh = blockIdx.x & 1, btn = blockIdx.x >> 1;
    int b = btn / TN;
    int bm0 = btn * AL + mh * 5;
    float* sq    = smem;                        // [32][308] raw q rows
    float* sa    = smem + 32 * 308;             // [5][304] raw a rows
    float* a3    = smem + 32 * 308 + 5 * 304;   // [6][304] (row 5 dummy=0)
    float* s_qw2 = a3 + 6 * 304;                // [32] W2.q_n
    float* s_aw1 = s_qw2 + 32;                  // [8]  W1.a_n
    float* s_scA = s_aw1 + 8;                   // [8]  a scales

    // stage raw rows (emb rows are 1200B = 16B-aligned)
    for (int i = tid; i < 32 * 75; i += 256) {
      int r = i / 75, e4 = i % 75;
      int idx = q[b * QL + r];
      *(float4*)&sq[r * 308 + e4 * 4] =
          *(const float4*)&emb[(size_t)idx * E + e4 * 4];
    }
    for (int i = tid; i < 5 * 75; i += 256) {
      int j = i / 75, e4 = i % 75;
      int idx = alia[bm0 + j];
      *(float4*)&sa[j * 304 + e4 * 4] =
          *(const float4*)&emb[(size_t)idx * E + e4 * 4];
    }
    for (int i = tid; i < 304; i += 256) a3[5 * 304 + i] = 0.f;
    __syncthreads();

    // norm pass: 37 rows (32 q + 5 a), fused W2/W1 dot
    for (int r = wid; r < 37; r += 4) {
      bool isa = r >= 32;
      const float* row = isa ? &sa[(r - 32) * 304] : &sq[r * 308];
      const float* W = isa ? sim_w : (sim_w + E);
      float ss = 0.f, dw = 0.f;
      for (int e = lane; e < E; e += 64) {
        float v = row[e];
        ss += v * v;
        dw += v * W[e];
      }
      #pragma unroll
      for (int off = 32; off > 0; off >>= 1) {
        ss += __shfl_xor(ss, off);
        dw += __shfl_xor(dw, off);
      }
      if (lane == 0) {
        int idx = isa ? alia[bm0 + (r - 32)] : q[b * QL + r];
        float scale = (idx == 0) ? 0.f : (1.f / fmaxf(sqrtf(ss), 1e-12f));
        if (isa) { s_scA[r - 32] = scale; s_aw1[r - 32] = dw * scale; }
        else s_qw2[r] = dw * scale;
      }
    }
    __syncthreads();

    // a3 = a_n * W3; also write normalized aemb rows for k2b
    const float* w3 = sim_w + 2 * E;
    for (int i = tid; i < 5 * 75; i += 256) {
      int j = i / 75, e4 = i % 75;
      float sc = s_scA[j];
      float4 v = *(const float4*)&sa[j * 304 + e4 * 4];
      float4 wv = *(const float4*)&w3[e4 * 4];
      float4 vn; vn.x = v.x*sc; vn.y = v.y*sc; vn.z = v.z*sc; vn.w = v.w*sc;
      *(float4*)&ws[OFF_AEMB + (size_t)(bm0 + j) * SQS + e4 * 4] = vn;
      float4 a3v; a3v.x = vn.x*wv.x; a3v.y = vn.y*wv.y;
      a3v.z = vn.z*wv.z; a3v.w = vn.w*wv.w;
      *(float4*)&a3[j * 304 + e4 * 4] = a3v;
    }
    __syncthreads();

    // dot: wave w handles m-pair (2w, 2w+1); lane = (l=m-of-pair, g=q-idx).
    // sq read: 32 distinct b128 over all 8 superbanks (stride 308) = clean;
    // a3 read: 2-address broadcast. acc complete per lane -> shfl softmax.
    if (wid < 3) {
      int g = lane & 31, l = lane >> 5;
      int m = wid * 2 + l;              // 0..5 (5 = dummy, a3 row zero)
      float simb = sim_b[0];
      const float* qr = &sq[g * 308];
      const float* ar = &a3[m * 304];
      float acc = 0.f;
      for (int e4 = 0; e4 < 75; ++e4) {
        float4 qv = *(const float4*)&qr[e4 * 4];
        float4 av = *(const float4*)&ar[e4 * 4];
        acc += av.x*qv.x + av.y*qv.y + av.z*qv.z + av.w*qv.w;
      }
      if (m < 5) {
        int bm = bm0 + m;
        float att = s_aw1[m] + s_qw2[g] + acc + simb;
        if (!(alia[bm] != 0 && q[b * QL + g] != 0)) att = NEGV;
        ws[OFF_ATT + (size_t)bm * QL + g] = att;
        // softmax across the 32 g-lanes of this l-half (xor<=16 stays in half)
        float mx = att;
        #pragma unroll
        for (int off = 1; off < 32; off <<= 1) mx = fmaxf(mx, __shfl_xor(mx, off));
        float ex = expf(att - mx);
        float sm = ex;
        #pragma unroll
        for (int off = 1; off < 32; off <<= 1) sm += __shfl_xor(sm, off);
        ws[OFF_P + (size_t)bm * QL + g] = ex / sm;
      }
    }
  } else {
    // ================= role B: QW GEMM (512 x 300 @ 300 x 256) ============
    int rg = blockIdx.x - 320;
    int nh = rg & 1, rgi = rg >> 1;     // 64 rowgroups of 8 q-slots
    int slot0 = rgi * 8;
    float* sQ = smem;                   // [8][304] raw q rows
    float* spart = smem + 8 * 304;      // 8192
    float* s_scB = spart + 8192;        // [8]

    for (int i = tid; i < 8 * 75; i += 256) {
      int r = i / 75, e4 = i % 75;
      int idx = q[slot0 + r];
      *(float4*)&sQ[r * 304 + e4 * 4] =
          *(const float4*)&emb[(size_t)idx * E + e4 * 4];
    }
    __syncthreads();
    for (int r = wid; r < 8; r += 4) {
      const float* row = &sQ[r * 304];
      float ss = 0.f;
      for (int e = lane; e < E; e += 64) { float v = row[e]; ss += v * v; }
      #pragma unroll
      for (int off = 32; off > 0; off >>= 1) ss += __shfl_xor(ss, off);
      if (lane == 0) {
        int idx = q[slot0 + r];
        s_scB[r] = (idx == 0) ? 0.f : (1.f / fmaxf(sqrtf(ss), 1e-12f));
      }
    }
    __syncthreads();

    int c = tid & 31, kq = tid >> 5;
    int ks = kq * 40;
    int nch = (kq == 7) ? 5 : 10;       // 7*40 + 20 = 300
    float acc[8][4] = {};
    for (int ch = 0; ch < nch; ++ch) {
      int k = ks + ch * 4;
      float4 a[8];
      #pragma unroll
      for (int j = 0; j < 8; j++) a[j] = *(const float4*)&sQ[j * 304 + k];
      const float* wp = enc_w + (size_t)k * H + nh * 128 + c;
      #pragma unroll
      for (int e = 0; e < 4; e++) {
        float w0 = wp[e * H + 0];
        float w1 = wp[e * H + 32];
        float w2 = wp[e * H + 64];
        float w3v = wp[e * H + 96];
        #pragma unroll
        for (int j = 0; j < 8; j++) {
          float av = (e == 0) ? a[j].x : (e == 1) ? a[j].y
                   : (e == 2) ? a[j].z : a[j].w;
          acc[j][0] += av * w0; acc[j][1] += av * w1;
          acc[j][2] += av * w2; acc[j][3] += av * w3v;
        }
      }
    }
    #pragma unroll
    for (int j = 0; j < 8; j++)
      #pragma unroll
      for (int nc = 0; nc < 4; nc++)
        spart[((kq * 8 + j) * 4 + nc) * 32 + c] = acc[j][nc];
    __syncthreads();
    #pragma unroll
    for (int t = 0; t < 4; t++) {
      int o = tid + t * 256;
      int j = o >> 7, colh = o & 127;
      float s = 0.f;
      #pragma unroll
      for (int kk = 0; kk < 8; kk++)
        s += spart[((kk * 8 + j) * 4 + (colh >> 5)) * 32 + (colh & 31)];
      ws[OFF_QW + (size_t)(slot0 + j) * H + nh * 128 + colh] = s * s_scB[j];
    }
  }
}

// ---------------------------------------------------------------------------
// K2b: enc = relu(P@QW + aemb_n@W2enc + bias), summed over 5-row half, then
// dotted with qlin_w and block-reduced to one partial score PS[blk].
// grid = 640 blocks (btn, jh, nh), 256 threads = 32c x 8kq.
// ---------------------------------------------------------------------------
__global__ __launch_bounds__(256) void k2b_enc(
    const float* __restrict__ enc_w, const float* __restrict__ enc_b,
    const float* __restrict__ qlin_w, float* __restrict__ ws) {
  int blk = blockIdx.x;
  int nh = blk & 1, jh = (blk >> 1) & 1, btn = blk >> 2;
  int b = btn / TN;
  int tid = threadIdx.x;
  int c = tid & 31, kq = tid >> 5;
  int bm0 = btn * AL + jh * 5;

  __shared__ float sA[5 * 304];
  __shared__ float sP[5 * 32];
  __shared__ float spart[8 * 5 * 4 * 32];
  __shared__ float s_red[2];

  const float* ga = ws + OFF_AEMB + (size_t)bm0 * SQS;
  for (int i = tid; i < 5 * 75; i += 256) {
    int j = i / 75, e4 = i % 75;
    *(float4*)&sA[j * 304 + e4 * 4] = *(const float4*)&ga[j * SQS + e4 * 4];
  }
  if (tid < 160) sP[tid] = ws[OFF_P + (size_t)bm0 * QL + tid];
  __syncthreads();

  float acc[5][4] = {};

  // P @ QW part: this kq handles pk = kq*4 .. kq*4+3
  {
    float4 pv[5];
    #pragma unroll
    for (int j = 0; j < 5; j++) pv[j] = *(const float4*)&sP[j * 32 + kq * 4];
    const float* qwb = ws + OFF_QW + (size_t)(b * QL + kq * 4) * H + nh * 128 + c;
    #pragma unroll
    for (int pp = 0; pp < 4; pp++) {
      float w0 = qwb[pp * H + 0];
      float w1 = qwb[pp * H + 32];
      float w2 = qwb[pp * H + 64];
      float w3v = qwb[pp * H + 96];
      #pragma unroll
      for (int j = 0; j < 5; j++) {
        float p = (pp == 0) ? pv[j].x : (pp == 1) ? pv[j].y
                : (pp == 2) ? pv[j].z : pv[j].w;
        acc[j][0] += p * w0; acc[j][1] += p * w1;
        acc[j][2] += p * w2; acc[j][3] += p * w3v;
      }
    }
  }

  // aemb_n @ W2enc part
  int ks = kq * 40;
  int nch = (kq == 7) ? 5 : 10;         // 7*40 + 20 = 300
  for (int ch = 0; ch < nch; ++ch) {
    int k = ks + ch * 4;
    float4 a[5];
    #pragma unroll
    for (int j = 0; j < 5; j++) a[j] = *(const float4*)&sA[j * 304 + k];
    const float* wp = enc_w + (size_t)(E + k) * H + nh * 128 + c;
    #pragma unroll
    for (int e = 0; e < 4; e++) {
      float w0 = wp[e * H + 0];
      float w1 = wp[e * H + 32];
      float w2 = wp[e * H + 64];
      float w3v = wp[e * H + 96];
      #pragma unroll
      for (int j = 0; j < 5; j++) {
        float av = (e == 0) ? a[j].x : (e == 1) ? a[j].y
                 : (e == 2) ? a[j].z : a[j].w;
        acc[j][0] += av * w0; acc[j][1] += av * w1;
        acc[j][2] += av * w2; acc[j][3] += av * w3v;
      }
    }
  }

  #pragma unroll
  for (int j = 0; j < 5; j++)
    #pragma unroll
    for (int nc = 0; nc < 4; nc++)
      spart[((kq * 5 + j) * 4 + nc) * 32 + c] = acc[j][nc];
  __syncthreads();

  float v = 0.f;
  if (tid < 128) {
    int colh = tid, col = nh * 128 + colh;
    float bias = enc_b[col];
    float s = 0.f;
    #pragma unroll
    for (int j = 0; j < 5; j++) {
      float t = bias;
      #pragma unroll
      for (int kk = 0; kk < 8; kk++)
        t += spart[((kk * 5 + j) * 4 + (colh >> 5)) * 32 + (colh & 31)];
      s += fmaxf(t, 0.f);
    }
    v = s * qlin_w[col];
  }
  #pragma unroll
  for (int off = 32; off > 0; off >>= 1) v += __shfl_down(v, off);
  if (tid < 128 && (tid & 63) == 0) s_red[tid >> 6] = v;
  __syncthreads();
  if (tid == 0) ws[OFF_PS + blk] = s_red[0] + s_red[1];
}

// ---------------------------------------------------------------------------
// K3: per-b epilogue (now tiny: PS partials + atten maxes).
// grid = B blocks, 256 threads.
// ---------------------------------------------------------------------------
__global__ __launch_bounds__(256) void k3_final(
    const float* __restrict__ els, const float* __restrict__ elo,
    const float* __restrict__ cate, const float* __restrict__ qlin_b,
    const float* __restrict__ cls_w, const float* __restrict__ cls_b,
    const float* __restrict__ ws, float* __restrict__ out) {
  int b = blockIdx.x;
  int tid = threadIdx.x;
  __shared__ float s_logit[TN], s_p[TN];
  __shared__ float s_at[M * QL];

  const float* attb = ws + OFF_ATT + (size_t)b * M * QL;
  for (int i = tid; i < 800; i += 256)
    *(float4*)&s_at[i * 4] = *(const float4*)&attb[i * 4];

  if (tid < TN) {
    const float* ps = ws + OFF_PS + (size_t)(b * TN + tid) * 4;
    float score = ps[0] + ps[1] + ps[2] + ps[3] + qlin_b[0];
    float lo = elo[b * TN + tid], ls = els[b * TN + tid];
    float c0 = cate[(b * TN + tid) * 2 + 0];
    float c1 = cate[(b * TN + tid) * 2 + 1];
    float logit = lo * cls_w[0] + ls * cls_w[1] + c0 * cls_w[2] +
                  c1 * cls_w[3] + score * cls_w[4] + cls_b[0];
    s_logit[tid] = ((ls + lo) != 0.0f) ? logit : NEGV;
  }
  __syncthreads();

  if (tid == 0) {
    float mx = -INFINITY;
    for (int t = 0; t < TN; t++) mx = fmaxf(mx, s_logit[t]);
    float sm = 0.f;
    for (int t = 0; t < TN; t++) sm += expf(s_logit[t] - mx);
    for (int t = 0; t < TN; t++) s_p[t] = expf(s_logit[t] - mx) / sm;
  }
  if (tid < TN) out[b * TN + tid] = s_logit[tid];
  __syncthreads();

  if (tid < QL) {
    float sacc = 0.f;
    for (int tn2 = 0; tn2 < TN; tn2++) {
      float mxa = -INFINITY;
      #pragma unroll
      for (int al = 0; al < AL; al++) {
        mxa = fmaxf(mxa, s_at[(tn2 * AL + al) * QL + tid]);
      }
      sacc += s_p[tn2] * mxa;
    }
    float mx = sacc;
    #pragma unroll
    for (int off = 16; off > 0; off >>= 1) mx = fmaxf(mx, __shfl_xor(mx, off, 32));
    float ex = expf(sacc - mx);
    float sm = ex;
    #pragma unroll
    for (int off = 16; off > 0; off >>= 1) sm += __shfl_xor(sm, off, 32);
    out[B * TN + b * QL + tid] = ex / sm;
  }
}

// ---------------------------------------------------------------------------
extern "C" void kernel_launch(void* const* d_in, const int* in_sizes, int n_in,
                              void* d_out, int out_size, void* d_ws, size_t ws_size,
                              hipStream_t stream) {
  const int*   q      = (const int*)  d_in[0];
  const int*   alia   = (const int*)  d_in[1];
  const float* els    = (const float*)d_in[2];
  const float* elo    = (const float*)d_in[3];
  const float* cate   = (const float*)d_in[4];
  const float* emb    = (const float*)d_in[5];
  const float* sim_w  = (const float*)d_in[6];
  const float* sim_b  = (const float*)d_in[7];
  const float* enc_w  = (const float*)d_in[8];
  const float* enc_b  = (const float*)d_in[9];
  const float* qlin_w = (const float*)d_in[10];
  const float* qlin_b = (const float*)d_in[11];
  const float* cls_w  = (const float*)d_in[12];
  const float* cls_b  = (const float*)d_in[13];
  float* out = (float*)d_out;
  float* ws  = (float*)d_ws;

  k2_fused<<<320 + 128, 256, 0, stream>>>(q, alia, emb, sim_w, sim_b, enc_w, ws);
  k2b_enc<<<B * TN * 4, 256, 0, stream>>>(enc_w, enc_b, qlin_w, ws);
  k3_final<<<B, 256, 0, stream>>>(els, elo, cate, qlin_b, cls_w, cls_b, ws, out);
}